// Round 3
// baseline (800.975 us; speedup 1.0000x reference)
//
#include <hip/hip_runtime.h>

// PointSetDifferenceModule: B=4, N=8192, C=64, K=16
//
// Math restructuring (all exact in infinite precision):
//  - b1 biases cancel under BatchNorm (mean subtraction) -> dropped.
//  - First linears commute with gather/subtract/weighted-sum:
//      G_d = F @ diff_w1^T, G_s = F @ sim_w1^T  (precomputed once)
//      y_diff[b,n,k] = G_d_self[b,n] - G_d_other[b,idx]
//      y_sim[b,n]    = sum_k softmax_k * G_s_other[b,idx_k]
//  - BN train-mode stats (biased var) computed via sum / sumsq atomically
//    accumulated from block partials, then scale = g*rsqrt(var+eps),
//    shift = beta - mu*scale.

#define Bn 4
#define Nn 8192
#define Cc 64
#define Kk 16
#define NPTS (Bn * Nn)        // 32768
#define NSAMP (NPTS * Kk)     // 524288
#define EPSf 1e-5f

// workspace layout (float offsets)
#define ACC_O 0       // 1024 floats: diff0[128] diff1[128] sim0[128] sim1[128] fin0[256] fin1[256]
#define SS_O 2048     // 1024 floats scale/shift, same segmenting
#define W2ST_O 4096   // 4096  : sim_w2^T   [j][c] 64x64
#define FW1T_O 8192   // 16384 : fin_w1^T   [j][c] 128x128
#define FW2T_O 24576  // 8192  : fin_w2^T   [j][c] 128x64
#define G_O 65536
#define GSZ (NPTS * Cc)  // 2097152 floats per array

// ---------------- small weight transposes ----------------
__global__ void prep_transpose(const float* __restrict__ w2s,
                               const float* __restrict__ fw1,
                               const float* __restrict__ fw2,
                               float* __restrict__ ws) {
  int t = blockIdx.x * 256 + threadIdx.x;
  int stride = gridDim.x * 256;
  for (int i = t; i < 64 * 64; i += stride) {
    int c = i >> 6, j = i & 63;
    ws[W2ST_O + j * 64 + c] = w2s[c * 64 + j];
  }
  for (int i = t; i < 128 * 128; i += stride) {
    int c = i >> 7, j = i & 127;
    ws[FW1T_O + j * 128 + c] = fw1[c * 128 + j];
  }
  for (int i = t; i < 64 * 128; i += stride) {
    int c = i >> 7, j = i & 127;  // fw2 is (64,128)
    ws[FW2T_O + j * 64 + c] = fw2[c * 128 + j];
  }
}

// ---------------- G = F @ W^T  (64x64 tiles) ----------------
__global__ __launch_bounds__(256) void gemmG(const float* __restrict__ f0,
                                             const float* __restrict__ f1,
                                             const float* __restrict__ wd,
                                             const float* __restrict__ wsim,
                                             float* __restrict__ ws) {
  int z = blockIdx.z;
  const float* F = (z & 1) ? f1 : f0;
  const float* W = (z >> 1) ? wsim : wd;
  float* G = ws + G_O + (size_t)z * GSZ;
  __shared__ float Wl[64][65];
  __shared__ float Fl[64][65];
  int t = threadIdx.x;
#pragma unroll
  for (int i = 0; i < 16; i++) {
    int ix = t + i * 256;
    Wl[ix >> 6][ix & 63] = W[ix];
  }
  int ptbase = blockIdx.x * 64;
#pragma unroll
  for (int i = 0; i < 16; i++) {
    int ix = t + i * 256;
    Fl[ix >> 6][ix & 63] = F[(size_t)ptbase * 64 + ix];
  }
  __syncthreads();
  int ty = t >> 4, tx = t & 15;
  int r0 = ty * 4, c0 = tx * 4;
  float acc[4][4] = {};
#pragma unroll 4
  for (int j = 0; j < 64; ++j) {
    float a[4], w[4];
#pragma unroll
    for (int i = 0; i < 4; i++) a[i] = Fl[r0 + i][j];
#pragma unroll
    for (int m = 0; m < 4; m++) w[m] = Wl[c0 + m][j];
#pragma unroll
    for (int i = 0; i < 4; i++)
#pragma unroll
      for (int m = 0; m < 4; m++) acc[i][m] += a[i] * w[m];
  }
#pragma unroll
  for (int i = 0; i < 4; i++) {
    float4 v = make_float4(acc[i][0], acc[i][1], acc[i][2], acc[i][3]);
    *reinterpret_cast<float4*>(G + (size_t)(ptbase + r0 + i) * 64 + c0) = v;
  }
}

// ---------------- per-direction: diff stats + sim softmax + y_sim ----------------
// one wave per point, grid-stride. grid MUST stay 1024 blocks (uniform trips).
__global__ __launch_bounds__(256) void stats_sim(
    const float* __restrict__ f_self, const float* __restrict__ f_other,
    const float* __restrict__ gd_self, const float* __restrict__ gd_other,
    const float* __restrict__ gs_other, const int* __restrict__ idx,
    float* __restrict__ ysim_out, float* __restrict__ accDiff,
    float* __restrict__ accSim) {
  int lane = threadIdx.x & 63, wave = threadIdx.x >> 6;
  int gw = blockIdx.x * 4 + wave, nw = gridDim.x * 4;
  float sd = 0.f, qd = 0.f, ssm = 0.f, qsm = 0.f;
  for (int pt = gw; pt < NPTS; pt += nw) {
    int bbase = (pt >> 13) * Nn;
    float fs = f_self[pt * 64 + lane];
    float gds = gd_self[pt * 64 + lane];
    int myidx = idx[pt * 16 + (lane & 15)];
    float sims[16], gso[16];
#pragma unroll
    for (int k = 0; k < 16; k++) {
      int j = __shfl(myidx, k);
      int rowo = (bbase + j) * 64 + lane;
      float fov = f_other[rowo];
      float gdo = gd_other[rowo];
      gso[k] = gs_other[rowo];
      float p = fs * fov;
#pragma unroll
      for (int off = 32; off >= 1; off >>= 1) p += __shfl_xor(p, off);
      sims[k] = p;
      float y = gds - gdo;
      sd += y;
      qd += y * y;
    }
    float m = sims[0];
#pragma unroll
    for (int k = 1; k < 16; k++) m = fmaxf(m, sims[k]);
    float den = 0.f, e[16];
#pragma unroll
    for (int k = 0; k < 16; k++) {
      e[k] = __expf(sims[k] - m);
      den += e[k];
    }
    float inv = 1.f / den;
    float ysim = 0.f;
#pragma unroll
    for (int k = 0; k < 16; k++) ysim += e[k] * gso[k];
    ysim *= inv;
    ysim_out[pt * 64 + lane] = ysim;
    ssm += ysim;
    qsm += ysim * ysim;
  }
  __shared__ float red[4][64];
#define BRED(val, tgt)                                                      \
  red[wave][lane] = (val);                                                  \
  __syncthreads();                                                          \
  if (wave == 0)                                                            \
    atomicAdd((tgt) + lane,                                                 \
              red[0][lane] + red[1][lane] + red[2][lane] + red[3][lane]);   \
  __syncthreads();
  BRED(sd, accDiff)
  BRED(qd, accDiff + 64)
  BRED(ssm, accSim)
  BRED(qsm, accSim + 64)
#undef BRED
}

// ---------------- finalize diff0,diff1,sim0,sim1 ----------------
__global__ void finalize1(const float* __restrict__ acc, const float* __restrict__ dg,
                          const float* __restrict__ dbeta, const float* __restrict__ sg,
                          const float* __restrict__ sbeta, float* __restrict__ ss) {
  int t = threadIdx.x;
  int seg = t >> 6, c = t & 63;
  const float* a = acc + seg * 128;
  float cnt = (seg < 2) ? (float)NSAMP : (float)NPTS;
  float mu = a[c] / cnt;
  float var = a[64 + c] / cnt - mu * mu;
  const float* g = (seg < 2) ? dg : sg;
  const float* be = (seg < 2) ? dbeta : sbeta;
  float scale = g[c] * rsqrtf(var + EPSf);
  ss[seg * 128 + c] = scale;
  ss[seg * 128 + 64 + c] = be[c] - mu * scale;
}

// ---------------- per-direction diff output: h=relu(ss(y)), Z=h@W2^T, max over K ----------------
__global__ __launch_bounds__(256) void diff_out_k(
    const float* __restrict__ gd_self, const float* __restrict__ gd_other,
    const int* __restrict__ idx, const float* __restrict__ w2d,
    const float* __restrict__ b2d, const float* __restrict__ ssd,
    float* __restrict__ dout) {
  __shared__ float Wl[64][65];
  __shared__ float Ht[64][65];
  __shared__ float Gs[4][64];
  __shared__ int idxt[64];
  __shared__ float sc[64], sh[64], bb[64];
  int t = threadIdx.x;
#pragma unroll
  for (int i = 0; i < 16; i++) {
    int ix = t + i * 256;
    Wl[ix >> 6][ix & 63] = w2d[ix];
  }
  if (t < 64) {
    sc[t] = ssd[t];
    sh[t] = ssd[64 + t];
    bb[t] = b2d[t];
  }
  int ty = t >> 4, tx = t & 15, r0 = ty * 4, c0 = tx * 4;
  int wave = t >> 6;
  int r = t >> 2, q = t & 3;
  for (int tile = blockIdx.x; tile < NPTS / 4; tile += gridDim.x) {
    int ptb = tile * 4;
    __syncthreads();  // protect Ht/idxt reuse across tiles (and after wl load)
    if (t < 64) idxt[t] = idx[ptb * 16 + t];
    Gs[t >> 6][t & 63] = gd_self[(size_t)ptb * 64 + t];
    __syncthreads();
    int p = r >> 4;
    int bbase = ((ptb + p) >> 13) * Nn;
    const float* go = gd_other + (size_t)(bbase + idxt[r]) * 64 + q * 16;
#pragma unroll
    for (int e4 = 0; e4 < 4; e4++) {
      float4 v = *reinterpret_cast<const float4*>(go + e4 * 4);
      float vv[4] = {v.x, v.y, v.z, v.w};
#pragma unroll
      for (int i = 0; i < 4; i++) {
        int c = q * 16 + e4 * 4 + i;
        float y = Gs[p][c] - vv[i];
        Ht[r][c] = fmaxf(sc[c] * y + sh[c], 0.f);
      }
    }
    __syncthreads();
    float acc[4][4] = {};
#pragma unroll 4
    for (int j = 0; j < 64; ++j) {
      float a[4], w[4];
#pragma unroll
      for (int i = 0; i < 4; i++) a[i] = Ht[r0 + i][j];
#pragma unroll
      for (int m = 0; m < 4; m++) w[m] = Wl[c0 + m][j];
#pragma unroll
      for (int i = 0; i < 4; i++)
#pragma unroll
        for (int m = 0; m < 4; m++) acc[i][m] += a[i] * w[m];
    }
    float mx[4];
#pragma unroll
    for (int m = 0; m < 4; m++) {
      mx[m] = fmaxf(fmaxf(acc[0][m], acc[1][m]), fmaxf(acc[2][m], acc[3][m]));
      mx[m] = fmaxf(mx[m], __shfl_xor(mx[m], 16));
      mx[m] = fmaxf(mx[m], __shfl_xor(mx[m], 32));
    }
    if ((ty & 3) == 0) {
      float4 o = make_float4(mx[0] + bb[c0], mx[1] + bb[c0 + 1],
                             mx[2] + bb[c0 + 2], mx[3] + bb[c0 + 3]);
      *reinterpret_cast<float4*>(dout + (size_t)(ptb + wave) * 64 + c0) = o;
    }
  }
}

// ---------------- per-direction: simfeat + concat + y_fin + fin stats ----------------
// grid MUST stay 1024 blocks (uniform trip count for in-loop barriers).
__global__ __launch_bounds__(256) void simfin(
    const float* __restrict__ ysim, const float* __restrict__ sss,
    const float* __restrict__ b2s, const float* __restrict__ diffout,
    const float* __restrict__ w2sT, const float* __restrict__ fw1T,
    float* __restrict__ simfeat, float* __restrict__ accFin) {
  int lane = threadIdx.x & 63, wave = threadIdx.x >> 6;
  int gw = blockIdx.x * 4 + wave, nw = gridDim.x * 4;
  __shared__ float hw[4][64];
  __shared__ float cw[4][128];
  float scl = sss[lane], shf = sss[64 + lane];
  float b2v = b2s[lane];
  float s0 = 0.f, q0 = 0.f, s1 = 0.f, q1 = 0.f;
  for (int pt = gw; pt < NPTS; pt += nw) {
    float h = fmaxf(scl * ysim[pt * 64 + lane] + shf, 0.f);
    hw[wave][lane] = h;
    __syncthreads();
    float a = b2v;
#pragma unroll 4
    for (int j = 0; j < 64; j++) a += hw[wave][j] * w2sT[j * 64 + lane];
    simfeat[pt * 64 + lane] = a;
    cw[wave][lane] = diffout[pt * 64 + lane];
    cw[wave][64 + lane] = a;
    __syncthreads();
    float y0 = 0.f, y1 = 0.f;
#pragma unroll 4
    for (int j = 0; j < 128; j++) {
      float cj = cw[wave][j];
      y0 += cj * fw1T[j * 128 + lane];
      y1 += cj * fw1T[j * 128 + 64 + lane];
    }
    s0 += y0;
    q0 += y0 * y0;
    s1 += y1;
    q1 += y1 * y1;
    __syncthreads();
  }
  __shared__ float red[4][64];
#define BRED(val, tgt)                                                      \
  red[wave][lane] = (val);                                                  \
  __syncthreads();                                                          \
  if (wave == 0)                                                            \
    atomicAdd((tgt) + lane,                                                 \
              red[0][lane] + red[1][lane] + red[2][lane] + red[3][lane]);   \
  __syncthreads();
  BRED(s0, accFin)
  BRED(s1, accFin + 64)
  BRED(q0, accFin + 128)
  BRED(q1, accFin + 192)
#undef BRED
}

// ---------------- finalize fin0, fin1 ----------------
__global__ void finalize2(const float* __restrict__ accF, const float* __restrict__ fg,
                          const float* __restrict__ fbeta, float* __restrict__ ssF) {
  int t = threadIdx.x;
  int seg = t >> 7, c = t & 127;
  const float* a = accF + seg * 256;
  float mu = a[c] / (float)NPTS;
  float var = a[128 + c] / (float)NPTS - mu * mu;
  float scale = fg[c] * rsqrtf(var + EPSf);
  ssF[seg * 256 + c] = scale;
  ssF[seg * 256 + 128 + c] = fbeta[c] - mu * scale;
}

// ---------------- per-direction final output ----------------
// grid MUST stay 1024 blocks (uniform trip count for in-loop barriers).
__global__ __launch_bounds__(256) void finalout(
    const float* __restrict__ diffout, const float* __restrict__ simfeat,
    const float* __restrict__ ssf, const float* __restrict__ fw1T,
    const float* __restrict__ fw2T, const float* __restrict__ fb2,
    float* __restrict__ out) {
  int lane = threadIdx.x & 63, wave = threadIdx.x >> 6;
  int gw = blockIdx.x * 4 + wave, nw = gridDim.x * 4;
  __shared__ float cw[4][128];
  __shared__ float hf[4][128];
  float sc0 = ssf[lane], sc1 = ssf[64 + lane];
  float sh0 = ssf[128 + lane], sh1 = ssf[192 + lane];
  float b2v = fb2[lane];
  for (int pt = gw; pt < NPTS; pt += nw) {
    cw[wave][lane] = diffout[pt * 64 + lane];
    cw[wave][64 + lane] = simfeat[pt * 64 + lane];
    __syncthreads();
    float y0 = 0.f, y1 = 0.f;
#pragma unroll 4
    for (int j = 0; j < 128; j++) {
      float cj = cw[wave][j];
      y0 += cj * fw1T[j * 128 + lane];
      y1 += cj * fw1T[j * 128 + 64 + lane];
    }
    hf[wave][lane] = fmaxf(sc0 * y0 + sh0, 0.f);
    hf[wave][64 + lane] = fmaxf(sc1 * y1 + sh1, 0.f);
    __syncthreads();
    float o = b2v;
#pragma unroll 4
    for (int j = 0; j < 128; j++) o += hf[wave][j] * fw2T[j * 64 + lane];
    out[pt * 64 + lane] = o;
    __syncthreads();
  }
}

extern "C" void kernel_launch(void* const* d_in, const int* in_sizes, int n_in,
                              void* d_out, int out_size, void* d_ws, size_t ws_size,
                              hipStream_t stream) {
  const float* f0 = (const float*)d_in[0];
  const float* f1 = (const float*)d_in[1];
  const int* i01 = (const int*)d_in[2];
  const int* i10 = (const int*)d_in[3];
  const float* dw1 = (const float*)d_in[4];
  const float* dg = (const float*)d_in[6];
  const float* dbe = (const float*)d_in[7];
  const float* dw2 = (const float*)d_in[8];
  const float* db2 = (const float*)d_in[9];
  const float* sw1 = (const float*)d_in[10];
  const float* sg = (const float*)d_in[12];
  const float* sbe = (const float*)d_in[13];
  const float* sw2 = (const float*)d_in[14];
  const float* sb2 = (const float*)d_in[15];
  const float* fw1 = (const float*)d_in[16];
  const float* fg = (const float*)d_in[18];
  const float* fbe = (const float*)d_in[19];
  const float* fw2 = (const float*)d_in[20];
  const float* fb2 = (const float*)d_in[21];

  float* ws = (float*)d_ws;
  float* out = (float*)d_out;

  float* acc = ws + ACC_O;
  float* ss = ws + SS_O;
  float* w2sT = ws + W2ST_O;
  float* fw1T = ws + FW1T_O;
  float* fw2T = ws + FW2T_O;
  float* GD0 = ws + G_O;
  float* GD1 = GD0 + GSZ;
  float* GS0 = GD1 + GSZ;
  float* GS1 = GS0 + GSZ;
  float* YS0 = GS1 + GSZ;
  float* YS1 = YS0 + GSZ;
  float* DF0 = YS1 + GSZ;
  float* DF1 = DF0 + GSZ;
  float* SF0 = DF1 + GSZ;
  float* SF1 = SF0 + GSZ;

  hipMemsetAsync(acc, 0, 1024 * sizeof(float), stream);
  prep_transpose<<<dim3(28), 256, 0, stream>>>(sw2, fw1, fw2, ws);
  gemmG<<<dim3(512, 1, 4), 256, 0, stream>>>(f0, f1, dw1, sw1, ws);

  stats_sim<<<1024, 256, 0, stream>>>(f0, f1, GD0, GD1, GS1, i01, YS0, acc + 0, acc + 256);
  stats_sim<<<1024, 256, 0, stream>>>(f1, f0, GD1, GD0, GS0, i10, YS1, acc + 128, acc + 384);

  finalize1<<<1, 256, 0, stream>>>(acc, dg, dbe, sg, sbe, ss);

  diff_out_k<<<2048, 256, 0, stream>>>(GD0, GD1, i01, dw2, db2, ss + 0, DF0);
  diff_out_k<<<2048, 256, 0, stream>>>(GD1, GD0, i10, dw2, db2, ss + 128, DF1);

  simfin<<<1024, 256, 0, stream>>>(YS0, ss + 256, sb2, DF0, w2sT, fw1T, SF0, acc + 512);
  simfin<<<1024, 256, 0, stream>>>(YS1, ss + 384, sb2, DF1, w2sT, fw1T, SF1, acc + 768);

  finalize2<<<1, 256, 0, stream>>>(acc + 512, fg, fbe, ss + 512);

  finalout<<<1024, 256, 0, stream>>>(DF0, SF0, ss + 512, fw1T, fw2T, fb2, out);
  finalout<<<1024, 256, 0, stream>>>(DF1, SF1, ss + 768, fw1T, fw2T, fb2, out + (size_t)NPTS * 64);
}

// Round 4
// 491.719 us; speedup vs baseline: 1.6289x; 1.6289x over previous
//
#include <hip/hip_runtime.h>

// PointSetDifferenceModule: B=4, N=8192, C=64, K=16
//
// Math restructuring (exact):
//  - b1 biases cancel under BatchNorm -> dropped.
//  - First linears commute with gather/subtract/weighted-sum:
//      G_d = F @ diff_w1^T, G_s = F @ sim_w1^T  (precomputed once)
//  - BN stats via sum/sumsq atomics -> scale/shift.
//  - Tail MLPs are proper 64-pt-tile GEMMs (weights staged in LDS once/block).
//  - yfin stored (not recomputed); aliased over dead GS/YS regions.

#define Bn 4
#define Nn 8192
#define NPTS (Bn * Nn)        // 32768
#define NSAMP (NPTS * 16)     // 524288
#define EPSf 1e-5f

#define ACC_O 0       // 1024 floats of stats accumulators
#define SS_O 2048     // 1024 floats scale/shift
#define G_O 65536
#define GSZ (NPTS * 64)  // 2097152 floats per 64-ch array

// ---------------- G = F @ W^T  (64x64 tiles) ----------------
__global__ __launch_bounds__(256) void gemmG(const float* __restrict__ f0,
                                             const float* __restrict__ f1,
                                             const float* __restrict__ wd,
                                             const float* __restrict__ wsim,
                                             float* __restrict__ ws) {
  int z = blockIdx.z;
  const float* F = (z & 1) ? f1 : f0;
  const float* W = (z >> 1) ? wsim : wd;
  float* G = ws + G_O + (size_t)z * GSZ;
  __shared__ float Wl[64][65];
  __shared__ float Fl[64][65];
  int t = threadIdx.x;
#pragma unroll
  for (int i = 0; i < 16; i++) {
    int ix = t + i * 256;
    Wl[ix >> 6][ix & 63] = W[ix];
  }
  int ptbase = blockIdx.x * 64;
#pragma unroll
  for (int i = 0; i < 16; i++) {
    int ix = t + i * 256;
    Fl[ix >> 6][ix & 63] = F[(size_t)ptbase * 64 + ix];
  }
  __syncthreads();
  int ty = t >> 4, tx = t & 15;
  int r0 = ty * 4, c0 = tx * 4;
  float acc[4][4] = {};
#pragma unroll 4
  for (int j = 0; j < 64; ++j) {
    float a[4], w[4];
#pragma unroll
    for (int i = 0; i < 4; i++) a[i] = Fl[r0 + i][j];
#pragma unroll
    for (int m = 0; m < 4; m++) w[m] = Wl[c0 + m][j];
#pragma unroll
    for (int i = 0; i < 4; i++)
#pragma unroll
      for (int m = 0; m < 4; m++) acc[i][m] += a[i] * w[m];
  }
#pragma unroll
  for (int i = 0; i < 4; i++) {
    float4 v = make_float4(acc[i][0], acc[i][1], acc[i][2], acc[i][3]);
    *reinterpret_cast<float4*>(G + (size_t)(ptbase + r0 + i) * 64 + c0) = v;
  }
}

// ---------------- per-direction: diff stats + sim softmax + y_sim ----------------
__global__ __launch_bounds__(256) void stats_sim(
    const float* __restrict__ f_self, const float* __restrict__ f_other,
    const float* __restrict__ gd_self, const float* __restrict__ gd_other,
    const float* __restrict__ gs_other, const int* __restrict__ idx,
    float* __restrict__ ysim_out, float* __restrict__ accDiff,
    float* __restrict__ accSim) {
  int lane = threadIdx.x & 63, wave = threadIdx.x >> 6;
  int gw = blockIdx.x * 4 + wave, nw = gridDim.x * 4;
  float sd = 0.f, qd = 0.f, ssm = 0.f, qsm = 0.f;
  for (int pt = gw; pt < NPTS; pt += nw) {
    int bbase = (pt >> 13) * Nn;
    float fs = f_self[pt * 64 + lane];
    float gds = gd_self[pt * 64 + lane];
    int myidx = idx[pt * 16 + (lane & 15)];
    float sims[16], gso[16];
#pragma unroll
    for (int k = 0; k < 16; k++) {
      int j = __shfl(myidx, k);
      int rowo = (bbase + j) * 64 + lane;
      float fov = f_other[rowo];
      float gdo = gd_other[rowo];
      gso[k] = gs_other[rowo];
      float p = fs * fov;
#pragma unroll
      for (int off = 32; off >= 1; off >>= 1) p += __shfl_xor(p, off);
      sims[k] = p;
      float y = gds - gdo;
      sd += y;
      qd += y * y;
    }
    float m = sims[0];
#pragma unroll
    for (int k = 1; k < 16; k++) m = fmaxf(m, sims[k]);
    float den = 0.f, e[16];
#pragma unroll
    for (int k = 0; k < 16; k++) {
      e[k] = __expf(sims[k] - m);
      den += e[k];
    }
    float inv = 1.f / den;
    float ysim = 0.f;
#pragma unroll
    for (int k = 0; k < 16; k++) ysim += e[k] * gso[k];
    ysim *= inv;
    ysim_out[pt * 64 + lane] = ysim;
    ssm += ysim;
    qsm += ysim * ysim;
  }
  __shared__ float red[4][64];
#define BRED(val, tgt)                                                      \
  red[wave][lane] = (val);                                                  \
  __syncthreads();                                                          \
  if (wave == 0)                                                            \
    atomicAdd((tgt) + lane,                                                 \
              red[0][lane] + red[1][lane] + red[2][lane] + red[3][lane]);   \
  __syncthreads();
  BRED(sd, accDiff)
  BRED(qd, accDiff + 64)
  BRED(ssm, accSim)
  BRED(qsm, accSim + 64)
#undef BRED
}

// ---------------- finalize diff0,diff1,sim0,sim1 ----------------
__global__ void finalize1(const float* __restrict__ acc, const float* __restrict__ dg,
                          const float* __restrict__ dbeta, const float* __restrict__ sg,
                          const float* __restrict__ sbeta, float* __restrict__ ss) {
  int t = threadIdx.x;
  int seg = t >> 6, c = t & 63;
  const float* a = acc + seg * 128;
  float cnt = (seg < 2) ? (float)NSAMP : (float)NPTS;
  float mu = a[c] / cnt;
  float var = a[64 + c] / cnt - mu * mu;
  const float* g = (seg < 2) ? dg : sg;
  const float* be = (seg < 2) ? dbeta : sbeta;
  float scale = g[c] * rsqrtf(var + EPSf);
  ss[seg * 128 + c] = scale;
  ss[seg * 128 + 64 + c] = be[c] - mu * scale;
}

// ---------------- per-direction diff output (gather + GEMM + max over K) ----------------
__global__ __launch_bounds__(256) void diff_out_k(
    const float* __restrict__ gd_self, const float* __restrict__ gd_other,
    const int* __restrict__ idx, const float* __restrict__ w2d,
    const float* __restrict__ b2d, const float* __restrict__ ssd,
    float* __restrict__ dout) {
  __shared__ float Wl[64][65];
  __shared__ float Ht[64][65];
  __shared__ float Gs[4][64];
  __shared__ int idxt[64];
  __shared__ float sc[64], sh[64], bb[64];
  int t = threadIdx.x;
#pragma unroll
  for (int i = 0; i < 16; i++) {
    int ix = t + i * 256;
    Wl[ix >> 6][ix & 63] = w2d[ix];
  }
  if (t < 64) {
    sc[t] = ssd[t];
    sh[t] = ssd[64 + t];
    bb[t] = b2d[t];
  }
  int ty = t >> 4, tx = t & 15, r0 = ty * 4, c0 = tx * 4;
  int wave = t >> 6;
  int r = t >> 2, q = t & 3;
  for (int tile = blockIdx.x; tile < NPTS / 4; tile += gridDim.x) {
    int ptb = tile * 4;
    __syncthreads();
    if (t < 64) idxt[t] = idx[ptb * 16 + t];
    Gs[t >> 6][t & 63] = gd_self[(size_t)ptb * 64 + t];
    __syncthreads();
    int p = r >> 4;
    int bbase = ((ptb + p) >> 13) * Nn;
    const float* go = gd_other + (size_t)(bbase + idxt[r]) * 64 + q * 16;
#pragma unroll
    for (int e4 = 0; e4 < 4; e4++) {
      float4 v = *reinterpret_cast<const float4*>(go + e4 * 4);
      float vv[4] = {v.x, v.y, v.z, v.w};
#pragma unroll
      for (int i = 0; i < 4; i++) {
        int c = q * 16 + e4 * 4 + i;
        float y = Gs[p][c] - vv[i];
        Ht[r][c] = fmaxf(sc[c] * y + sh[c], 0.f);
      }
    }
    __syncthreads();
    float acc[4][4] = {};
#pragma unroll 4
    for (int j = 0; j < 64; ++j) {
      float a[4], w[4];
#pragma unroll
      for (int i = 0; i < 4; i++) a[i] = Ht[r0 + i][j];
#pragma unroll
      for (int m = 0; m < 4; m++) w[m] = Wl[c0 + m][j];
#pragma unroll
      for (int i = 0; i < 4; i++)
#pragma unroll
        for (int m = 0; m < 4; m++) acc[i][m] += a[i] * w[m];
    }
    float mx[4];
#pragma unroll
    for (int m = 0; m < 4; m++) {
      mx[m] = fmaxf(fmaxf(acc[0][m], acc[1][m]), fmaxf(acc[2][m], acc[3][m]));
      mx[m] = fmaxf(mx[m], __shfl_xor(mx[m], 16));
      mx[m] = fmaxf(mx[m], __shfl_xor(mx[m], 32));
    }
    if ((ty & 3) == 0) {
      float4 o = make_float4(mx[0] + bb[c0], mx[1] + bb[c0 + 1],
                             mx[2] + bb[c0 + 2], mx[3] + bb[c0 + 3]);
      *reinterpret_cast<float4*>(dout + (size_t)(ptb + wave) * 64 + c0) = o;
    }
  }
}

// ---------------- SF = relu(bn(YS)) @ sw2^T + sb2  (tiled GEMM, K=64) ----------------
__global__ __launch_bounds__(256) void simfeat_gemm(
    const float* __restrict__ ysim, const float* __restrict__ ssS,
    const float* __restrict__ sw2, const float* __restrict__ sb2,
    float* __restrict__ sf) {
  __shared__ float Wl[64][65];
  __shared__ float Hl[64][65];
  __shared__ float sc[64], sh[64], bb[64];
  int t = threadIdx.x;
  if (t < 64) {
    sc[t] = ssS[t];
    sh[t] = ssS[64 + t];
    bb[t] = sb2[t];
  }
#pragma unroll
  for (int i = 0; i < 16; i++) {
    int ix = t + i * 256;
    Wl[ix >> 6][ix & 63] = sw2[ix];
  }
  __syncthreads();
  int ptb = blockIdx.x * 64;
#pragma unroll
  for (int i = 0; i < 16; i++) {
    int ix = t + i * 256;
    int row = ix >> 6, col = ix & 63;
    float v = ysim[(size_t)ptb * 64 + ix];
    Hl[row][col] = fmaxf(sc[col] * v + sh[col], 0.f);
  }
  __syncthreads();
  int ty = t >> 4, tx = t & 15, r0 = ty * 4, c0 = tx * 4;
  float acc[4][4] = {};
#pragma unroll 4
  for (int j = 0; j < 64; ++j) {
    float a[4], w[4];
#pragma unroll
    for (int i = 0; i < 4; i++) a[i] = Hl[r0 + i][j];
#pragma unroll
    for (int m = 0; m < 4; m++) w[m] = Wl[c0 + m][j];
#pragma unroll
    for (int i = 0; i < 4; i++)
#pragma unroll
      for (int m = 0; m < 4; m++) acc[i][m] += a[i] * w[m];
  }
#pragma unroll
  for (int i = 0; i < 4; i++) {
    float4 v = make_float4(acc[i][0] + bb[c0], acc[i][1] + bb[c0 + 1],
                           acc[i][2] + bb[c0 + 2], acc[i][3] + bb[c0 + 3]);
    *reinterpret_cast<float4*>(sf + (size_t)(ptb + r0 + i) * 64 + c0) = v;
  }
}

// ---------------- YF = [DF|SF] @ fw1^T  + fin BN stats (K=128, N split by y) ------------
__global__ __launch_bounds__(256) void yfin_gemm(
    const float* __restrict__ df, const float* __restrict__ sf,
    const float* __restrict__ fw1, float* __restrict__ yf,
    float* __restrict__ accF) {
  __shared__ float Wl[64][129];
  __shared__ float Cl[64][65];
  __shared__ float redS[64], redQ[64];
  int t = threadIdx.x;
  int y = blockIdx.y;
  if (t < 64) {
    redS[t] = 0.f;
    redQ[t] = 0.f;
  }
#pragma unroll
  for (int i = 0; i < 32; i++) {
    int ix = t + i * 256;  // 8192
    Wl[ix >> 7][ix & 127] = fw1[(size_t)(y * 64 + (ix >> 7)) * 128 + (ix & 127)];
  }
  int ptb = blockIdx.x * 64;
#pragma unroll
  for (int i = 0; i < 16; i++) {
    int ix = t + i * 256;
    Cl[ix >> 6][ix & 63] = df[(size_t)ptb * 64 + ix];
  }
  __syncthreads();
  int ty = t >> 4, tx = t & 15, r0 = ty * 4, c0 = tx * 4;
  float acc[4][4] = {};
#pragma unroll 4
  for (int j = 0; j < 64; ++j) {
    float a[4], w[4];
#pragma unroll
    for (int i = 0; i < 4; i++) a[i] = Cl[r0 + i][j];
#pragma unroll
    for (int m = 0; m < 4; m++) w[m] = Wl[c0 + m][j];
#pragma unroll
    for (int i = 0; i < 4; i++)
#pragma unroll
      for (int m = 0; m < 4; m++) acc[i][m] += a[i] * w[m];
  }
  __syncthreads();
#pragma unroll
  for (int i = 0; i < 16; i++) {
    int ix = t + i * 256;
    Cl[ix >> 6][ix & 63] = sf[(size_t)ptb * 64 + ix];
  }
  __syncthreads();
#pragma unroll 4
  for (int j = 0; j < 64; ++j) {
    float a[4], w[4];
#pragma unroll
    for (int i = 0; i < 4; i++) a[i] = Cl[r0 + i][j];
#pragma unroll
    for (int m = 0; m < 4; m++) w[m] = Wl[c0 + m][64 + j];
#pragma unroll
    for (int i = 0; i < 4; i++)
#pragma unroll
      for (int m = 0; m < 4; m++) acc[i][m] += a[i] * w[m];
  }
#pragma unroll
  for (int i = 0; i < 4; i++) {
    float4 v = make_float4(acc[i][0], acc[i][1], acc[i][2], acc[i][3]);
    *reinterpret_cast<float4*>(yf + (size_t)(ptb + r0 + i) * 128 + y * 64 + c0) = v;
  }
#pragma unroll
  for (int m = 0; m < 4; m++) {
    float s = acc[0][m] + acc[1][m] + acc[2][m] + acc[3][m];
    float q = acc[0][m] * acc[0][m] + acc[1][m] * acc[1][m] +
              acc[2][m] * acc[2][m] + acc[3][m] * acc[3][m];
    atomicAdd(&redS[c0 + m], s);
    atomicAdd(&redQ[c0 + m], q);
  }
  __syncthreads();
  if (t < 64) {
    atomicAdd(accF + y * 64 + t, redS[t]);
    atomicAdd(accF + 128 + y * 64 + t, redQ[t]);
  }
}

// ---------------- finalize fin0, fin1 ----------------
__global__ void finalize2(const float* __restrict__ accF, const float* __restrict__ fg,
                          const float* __restrict__ fbeta, float* __restrict__ ssF) {
  int t = threadIdx.x;
  int seg = t >> 7, c = t & 127;
  const float* a = accF + seg * 256;
  float mu = a[c] / (float)NPTS;
  float var = a[128 + c] / (float)NPTS - mu * mu;
  float scale = fg[c] * rsqrtf(var + EPSf);
  ssF[seg * 256 + c] = scale;
  ssF[seg * 256 + 128 + c] = fbeta[c] - mu * scale;
}

// ---------------- out = relu(bn(YF)) @ fw2^T + fb2  (K=128, two phases) --------------
__global__ __launch_bounds__(256) void finout_gemm(
    const float* __restrict__ yf, const float* __restrict__ ssF,
    const float* __restrict__ fw2, const float* __restrict__ fb2,
    float* __restrict__ outp) {
  __shared__ float Wl[64][129];
  __shared__ float Hl[64][65];
  __shared__ float scl[128], shf[128], bb[64];
  int t = threadIdx.x;
  if (t < 128) {
    scl[t] = ssF[t];
    shf[t] = ssF[128 + t];
  }
  if (t < 64) bb[t] = fb2[t];
#pragma unroll
  for (int i = 0; i < 32; i++) {
    int ix = t + i * 256;
    Wl[ix >> 7][ix & 127] = fw2[ix];  // fw2 is (64,128) row-major
  }
  __syncthreads();
  int ptb = blockIdx.x * 64;
  int ty = t >> 4, tx = t & 15, r0 = ty * 4, c0 = tx * 4;
  float acc[4][4] = {};
  // phase 0: channels 0..63
#pragma unroll
  for (int i = 0; i < 16; i++) {
    int ix = t + i * 256;
    int row = ix >> 6, jj = ix & 63;
    float v = yf[(size_t)(ptb + row) * 128 + jj];
    Hl[row][jj] = fmaxf(scl[jj] * v + shf[jj], 0.f);
  }
  __syncthreads();
#pragma unroll 4
  for (int j = 0; j < 64; ++j) {
    float a[4], w[4];
#pragma unroll
    for (int i = 0; i < 4; i++) a[i] = Hl[r0 + i][j];
#pragma unroll
    for (int m = 0; m < 4; m++) w[m] = Wl[c0 + m][j];
#pragma unroll
    for (int i = 0; i < 4; i++)
#pragma unroll
      for (int m = 0; m < 4; m++) acc[i][m] += a[i] * w[m];
  }
  __syncthreads();
  // phase 1: channels 64..127
#pragma unroll
  for (int i = 0; i < 16; i++) {
    int ix = t + i * 256;
    int row = ix >> 6, jj = ix & 63;
    float v = yf[(size_t)(ptb + row) * 128 + 64 + jj];
    Hl[row][jj] = fmaxf(scl[64 + jj] * v + shf[64 + jj], 0.f);
  }
  __syncthreads();
#pragma unroll 4
  for (int j = 0; j < 64; ++j) {
    float a[4], w[4];
#pragma unroll
    for (int i = 0; i < 4; i++) a[i] = Hl[r0 + i][j];
#pragma unroll
    for (int m = 0; m < 4; m++) w[m] = Wl[c0 + m][64 + j];
#pragma unroll
    for (int i = 0; i < 4; i++)
#pragma unroll
      for (int m = 0; m < 4; m++) acc[i][m] += a[i] * w[m];
  }
#pragma unroll
  for (int i = 0; i < 4; i++) {
    float4 v = make_float4(acc[i][0] + bb[c0], acc[i][1] + bb[c0 + 1],
                           acc[i][2] + bb[c0 + 2], acc[i][3] + bb[c0 + 3]);
    *reinterpret_cast<float4*>(outp + (size_t)(ptb + r0 + i) * 64 + c0) = v;
  }
}

extern "C" void kernel_launch(void* const* d_in, const int* in_sizes, int n_in,
                              void* d_out, int out_size, void* d_ws, size_t ws_size,
                              hipStream_t stream) {
  const float* f0 = (const float*)d_in[0];
  const float* f1 = (const float*)d_in[1];
  const int* i01 = (const int*)d_in[2];
  const int* i10 = (const int*)d_in[3];
  const float* dw1 = (const float*)d_in[4];
  const float* dg = (const float*)d_in[6];
  const float* dbe = (const float*)d_in[7];
  const float* dw2 = (const float*)d_in[8];
  const float* db2 = (const float*)d_in[9];
  const float* sw1 = (const float*)d_in[10];
  const float* sg = (const float*)d_in[12];
  const float* sbe = (const float*)d_in[13];
  const float* sw2 = (const float*)d_in[14];
  const float* sb2 = (const float*)d_in[15];
  const float* fw1 = (const float*)d_in[16];
  const float* fg = (const float*)d_in[18];
  const float* fbe = (const float*)d_in[19];
  const float* fw2 = (const float*)d_in[20];
  const float* fb2 = (const float*)d_in[21];

  float* ws = (float*)d_ws;
  float* out = (float*)d_out;

  float* acc = ws + ACC_O;
  float* ss = ws + SS_O;
  float* GD0 = ws + G_O;
  float* GD1 = GD0 + GSZ;
  float* GS0 = GD1 + GSZ;
  float* GS1 = GS0 + GSZ;
  float* YS0 = GS1 + GSZ;
  float* YS1 = YS0 + GSZ;
  float* DF0 = YS1 + GSZ;
  float* DF1 = DF0 + GSZ;
  float* SF0 = DF1 + GSZ;
  float* SF1 = SF0 + GSZ;
  // aliases (regions dead by the time these are written):
  float* YF0 = GS0;  // spans GS0+GS1 (2*GSZ), free after stats_sim x2
  float* YF1 = YS0;  // spans YS0+YS1 (2*GSZ), free after simfeat_gemm x2

  hipMemsetAsync(acc, 0, 1024 * sizeof(float), stream);
  gemmG<<<dim3(512, 1, 4), 256, 0, stream>>>(f0, f1, dw1, sw1, ws);

  stats_sim<<<1024, 256, 0, stream>>>(f0, f1, GD0, GD1, GS1, i01, YS0, acc + 0, acc + 256);
  stats_sim<<<1024, 256, 0, stream>>>(f1, f0, GD1, GD0, GS0, i10, YS1, acc + 128, acc + 384);

  finalize1<<<1, 256, 0, stream>>>(acc, dg, dbe, sg, sbe, ss);

  diff_out_k<<<2048, 256, 0, stream>>>(GD0, GD1, i01, dw2, db2, ss + 0, DF0);
  diff_out_k<<<2048, 256, 0, stream>>>(GD1, GD0, i10, dw2, db2, ss + 128, DF1);

  simfeat_gemm<<<512, 256, 0, stream>>>(YS0, ss + 256, sw2, sb2, SF0);
  simfeat_gemm<<<512, 256, 0, stream>>>(YS1, ss + 384, sw2, sb2, SF1);

  yfin_gemm<<<dim3(512, 2), 256, 0, stream>>>(DF0, SF0, fw1, YF0, acc + 512);
  yfin_gemm<<<dim3(512, 2), 256, 0, stream>>>(DF1, SF1, fw1, YF1, acc + 768);

  finalize2<<<1, 256, 0, stream>>>(acc + 512, fg, fbe, ss + 512);

  finout_gemm<<<512, 256, 0, stream>>>(YF0, ss + 512, fw2, fb2, out);
  finout_gemm<<<512, 256, 0, stream>>>(YF1, ss + 768, fw2, fb2, out + (size_t)NPTS * 64);
}

// Round 5
// 364.569 us; speedup vs baseline: 2.1970x; 1.3488x over previous
//
#include <hip/hip_runtime.h>

// PointSetDifferenceModule: B=4, N=8192, C=64, K=16
// Round 5: bf16 MFMA diff path + fused gather table.
//  FT[pt] row (512B): [ f fp32 x64 | G_d bf16 x64 | G_s bf16 x64 ]
//  diff stats & output both read bf16 G_d -> BN-consistent.

#define Bn 4
#define Nn 8192
#define NPTS (Bn * Nn)        // 32768
#define NSAMP (NPTS * 16)     // 524288
#define EPSf 1e-5f
#define FT_STRIDE 512         // bytes per point row
#define GSZ (NPTS * 64)       // floats per 64-ch fp32 array (8MB)

typedef __attribute__((ext_vector_type(8))) short v8bf;
typedef __attribute__((ext_vector_type(4))) float v4f;

__device__ inline unsigned pack_bf16x2(float a, float b) {
  unsigned ua = __float_as_uint(a), ub = __float_as_uint(b);
  ua = (ua + 0x7FFFu + ((ua >> 16) & 1u)) >> 16;
  ub = (ub + 0x7FFFu + ((ub >> 16) & 1u)) >> 16;
  return (ub << 16) | ua;
}
__device__ inline float bf16_lo(unsigned u) { return __uint_as_float(u << 16); }
__device__ inline float bf16_hi(unsigned u) { return __uint_as_float(u & 0xFFFF0000u); }

// ---------------- build fused tables: f fp32 copy + G_d, G_s bf16 ----------------
__global__ __launch_bounds__(256) void gemmG(const float* __restrict__ f0,
                                             const float* __restrict__ f1,
                                             const float* __restrict__ wd,
                                             const float* __restrict__ wsim,
                                             char* __restrict__ FT0,
                                             char* __restrict__ FT1) {
  int z = blockIdx.z;
  const float* F = z ? f1 : f0;
  char* FT = z ? FT1 : FT0;
  __shared__ float Fl[64][65];
  __shared__ float Wd[64][65];
  __shared__ float Ws[64][65];
  int t = threadIdx.x;
#pragma unroll
  for (int i = 0; i < 16; i++) {
    int ix = t + i * 256;
    Wd[ix >> 6][ix & 63] = wd[ix];
    Ws[ix >> 6][ix & 63] = wsim[ix];
  }
  int ptb = blockIdx.x * 64;
#pragma unroll
  for (int i = 0; i < 16; i++) {
    int ix = t + i * 256;
    float v = F[(size_t)ptb * 64 + ix];
    Fl[ix >> 6][ix & 63] = v;
    *(float*)(FT + (size_t)(ptb + (ix >> 6)) * FT_STRIDE + (ix & 63) * 4) = v;
  }
  __syncthreads();
  int ty = t >> 4, tx = t & 15, r0 = ty * 4, c0 = tx * 4;
  float ad[4][4] = {}, as_[4][4] = {};
#pragma unroll 4
  for (int j = 0; j < 64; ++j) {
    float a[4], w1[4], w2[4];
#pragma unroll
    for (int i = 0; i < 4; i++) a[i] = Fl[r0 + i][j];
#pragma unroll
    for (int m = 0; m < 4; m++) {
      w1[m] = Wd[c0 + m][j];
      w2[m] = Ws[c0 + m][j];
    }
#pragma unroll
    for (int i = 0; i < 4; i++)
#pragma unroll
      for (int m = 0; m < 4; m++) {
        ad[i][m] += a[i] * w1[m];
        as_[i][m] += a[i] * w2[m];
      }
  }
#pragma unroll
  for (int i = 0; i < 4; i++) {
    char* row = FT + (size_t)(ptb + r0 + i) * FT_STRIDE;
    uint2 gd2 = make_uint2(pack_bf16x2(ad[i][0], ad[i][1]),
                           pack_bf16x2(ad[i][2], ad[i][3]));
    *(uint2*)(row + 256 + c0 * 2) = gd2;
    uint2 gs2 = make_uint2(pack_bf16x2(as_[i][0], as_[i][1]),
                           pack_bf16x2(as_[i][2], as_[i][3]));
    *(uint2*)(row + 384 + c0 * 2) = gs2;
  }
}

// ---------------- diff stats + sim softmax + y_sim (half-wave per point) ----------------
__global__ __launch_bounds__(256) void stats_sim(
    const char* __restrict__ FT_self, const char* __restrict__ FT_other,
    const int* __restrict__ idx, float* __restrict__ ysim_out,
    float* __restrict__ accDiff, float* __restrict__ accSim) {
  int lane = threadIdx.x & 63, wave = threadIdx.x >> 6;
  int c2 = lane & 31;
  int half = lane >> 5;
  int hw = blockIdx.x * 8 + wave * 2 + half;
  int nhw = gridDim.x * 8;
  float sd0 = 0, sd1 = 0, qd0 = 0, qd1 = 0, ss0 = 0, ss1 = 0, qs0 = 0, qs1 = 0;
  for (int pt = hw; pt < NPTS; pt += nhw) {
    int bbase = (pt >> 13) * Nn;
    const char* srow = FT_self + (size_t)pt * FT_STRIDE;
    float2 fs = *(const float2*)(srow + c2 * 8);
    unsigned gds2 = *(const unsigned*)(srow + 256 + c2 * 4);
    float gds0 = bf16_lo(gds2), gds1 = bf16_hi(gds2);
    int myidx = 0;
    if (c2 < 16) myidx = idx[pt * 16 + c2];
    float sims[16];
    unsigned gsou[16];
#pragma unroll
    for (int k = 0; k < 16; k++) {
      int j = __shfl(myidx, (lane & 32) + k);
      const char* orow = FT_other + (size_t)(bbase + j) * FT_STRIDE;
      float2 fo = *(const float2*)(orow + c2 * 8);
      unsigned gdo2 = *(const unsigned*)(orow + 256 + c2 * 4);
      gsou[k] = *(const unsigned*)(orow + 384 + c2 * 4);
      float p = fs.x * fo.x + fs.y * fo.y;
      p += __shfl_xor(p, 16);
      p += __shfl_xor(p, 8);
      p += __shfl_xor(p, 4);
      p += __shfl_xor(p, 2);
      p += __shfl_xor(p, 1);
      sims[k] = p;
      float y0 = gds0 - bf16_lo(gdo2), y1 = gds1 - bf16_hi(gdo2);
      sd0 += y0; qd0 += y0 * y0;
      sd1 += y1; qd1 += y1 * y1;
    }
    float m = sims[0];
#pragma unroll
    for (int k = 1; k < 16; k++) m = fmaxf(m, sims[k]);
    float den = 0.f, y0 = 0.f, y1 = 0.f;
#pragma unroll
    for (int k = 0; k < 16; k++) {
      float e = __expf(sims[k] - m);
      den += e;
      y0 += e * bf16_lo(gsou[k]);
      y1 += e * bf16_hi(gsou[k]);
    }
    float inv = 1.f / den;
    y0 *= inv; y1 *= inv;
    *(float2*)(ysim_out + (size_t)pt * 64 + c2 * 2) = make_float2(y0, y1);
    ss0 += y0; qs0 += y0 * y0;
    ss1 += y1; qs1 += y1 * y1;
  }
  __shared__ float red[4][64][8];
  red[wave][lane][0] = sd0; red[wave][lane][1] = sd1;
  red[wave][lane][2] = qd0; red[wave][lane][3] = qd1;
  red[wave][lane][4] = ss0; red[wave][lane][5] = ss1;
  red[wave][lane][6] = qs0; red[wave][lane][7] = qs1;
  __syncthreads();
  if (wave == 0) {
#pragma unroll
    for (int qy = 0; qy < 8; qy++) {
      float v = red[0][lane][qy] + red[1][lane][qy] + red[2][lane][qy] + red[3][lane][qy];
      v += __shfl_xor(v, 32);
      if (lane < 32) {
        float* tgt = (qy < 4) ? accDiff : accSim;
        int q2 = qy & 3;
        atomicAdd(tgt + (q2 >> 1) * 64 + 2 * lane + (q2 & 1), v);
      }
    }
  }
}

// ---------------- finalize diff0,diff1,sim0,sim1 ----------------
__global__ void finalize1(const float* __restrict__ acc, const float* __restrict__ dg,
                          const float* __restrict__ dbeta, const float* __restrict__ sg,
                          const float* __restrict__ sbeta, float* __restrict__ ss) {
  int t = threadIdx.x;
  int seg = t >> 6, c = t & 63;
  const float* a = acc + seg * 128;
  float cnt = (seg < 2) ? (float)NSAMP : (float)NPTS;
  float mu = a[c] / cnt;
  float var = a[64 + c] / cnt - mu * mu;
  const float* g = (seg < 2) ? dg : sg;
  const float* be = (seg < 2) ? dbeta : sbeta;
  float scale = g[c] * rsqrtf(var + EPSf);
  ss[seg * 128 + c] = scale;
  ss[seg * 128 + 64 + c] = be[c] - mu * scale;
}

// ---------------- diff output: gather bf16 + BN/relu + MFMA GEMM + max over K --------
__global__ __launch_bounds__(256) void diff_out_k(
    const char* __restrict__ FT_self, const char* __restrict__ FT_other,
    const int* __restrict__ idx, const float* __restrict__ w2d,
    const float* __restrict__ b2d, const float* __restrict__ ssd,
    float* __restrict__ dout) {
  __shared__ __align__(16) unsigned WlU[64 * 36];  // W2 bf16, row n, k pairs, pad 36
  __shared__ __align__(16) unsigned HtU[64 * 36];  // h rows bf16
  __shared__ unsigned Gs[4][32];
  __shared__ int idxt[64];
  __shared__ float sc[64], sh[64], bb[64];
  int t = threadIdx.x;
  int r = t >> 2, q = t & 3;
  {
    const float4* w4 = (const float4*)(w2d + r * 64 + q * 16);
#pragma unroll
    for (int u = 0; u < 4; u++) {
      float4 v = w4[u];
      WlU[r * 36 + q * 8 + u * 2] = pack_bf16x2(v.x, v.y);
      WlU[r * 36 + q * 8 + u * 2 + 1] = pack_bf16x2(v.z, v.w);
    }
  }
  if (t < 64) {
    sc[t] = ssd[t];
    sh[t] = ssd[64 + t];
    bb[t] = b2d[t];
  }
  int wave = t >> 6, lane = t & 63;
  int lr = lane & 15, lg = lane >> 4;
  int p = r >> 4;
  for (int tile = blockIdx.x; tile < NPTS / 4; tile += gridDim.x) {
    int ptb = tile * 4;
    __syncthreads();  // protect HtU/idxt/Gs reuse (and first-iter Wl)
    if (t < 64) idxt[t] = idx[ptb * 16 + t];
    if (t < 128)
      Gs[t >> 5][t & 31] =
          *(const unsigned*)(FT_self + (size_t)(ptb + (t >> 5)) * FT_STRIDE + 256 + (t & 31) * 4);
    __syncthreads();
    int bbase = (ptb >> 13) * Nn;
    const char* orow = FT_other + (size_t)(bbase + idxt[r]) * FT_STRIDE + 256;
    uint4 g0 = *(const uint4*)(orow + q * 32);
    uint4 g1 = *(const uint4*)(orow + q * 32 + 16);
#pragma unroll
    for (int u = 0; u < 8; u++) {
      unsigned gdo2 = (u < 4) ? ((const unsigned*)&g0)[u] : ((const unsigned*)&g1)[u - 4];
      unsigned gds2 = Gs[p][q * 8 + u];
      int c = q * 16 + u * 2;
      float h0 = fmaxf(sc[c] * (bf16_lo(gds2) - bf16_lo(gdo2)) + sh[c], 0.f);
      float h1 = fmaxf(sc[c + 1] * (bf16_hi(gds2) - bf16_hi(gdo2)) + sh[c + 1], 0.f);
      HtU[r * 36 + q * 8 + u] = pack_bf16x2(h0, h1);
    }
    __syncthreads();
    v4f acc[4] = {{0, 0, 0, 0}, {0, 0, 0, 0}, {0, 0, 0, 0}, {0, 0, 0, 0}};
    v8bf a0 = *(const v8bf*)&HtU[(wave * 16 + lr) * 36 + lg * 4];
    v8bf a1 = *(const v8bf*)&HtU[(wave * 16 + lr) * 36 + 16 + lg * 4];
#pragma unroll
    for (int c = 0; c < 4; c++) {
      v8bf b0 = *(const v8bf*)&WlU[(c * 16 + lr) * 36 + lg * 4];
      v8bf b1 = *(const v8bf*)&WlU[(c * 16 + lr) * 36 + 16 + lg * 4];
      acc[c] = __builtin_amdgcn_mfma_f32_16x16x32_bf16(a0, b0, acc[c], 0, 0, 0);
      acc[c] = __builtin_amdgcn_mfma_f32_16x16x32_bf16(a1, b1, acc[c], 0, 0, 0);
    }
#pragma unroll
    for (int c = 0; c < 4; c++) {
      float mm = fmaxf(fmaxf(acc[c][0], acc[c][1]), fmaxf(acc[c][2], acc[c][3]));
      mm = fmaxf(mm, __shfl_xor(mm, 16));
      mm = fmaxf(mm, __shfl_xor(mm, 32));
      if (lane < 16) dout[(size_t)(ptb + wave) * 64 + c * 16 + lane] = mm + bb[c * 16 + lane];
    }
  }
}

// ---------------- SF = relu(bn(YS)) @ sw2^T + sb2 ----------------
__global__ __launch_bounds__(256) void simfeat_gemm(
    const float* __restrict__ ysim, const float* __restrict__ ssS,
    const float* __restrict__ sw2, const float* __restrict__ sb2,
    float* __restrict__ sf) {
  __shared__ float Wl[64][65];
  __shared__ float Hl[64][65];
  __shared__ float sc[64], sh[64], bb[64];
  int t = threadIdx.x;
  if (t < 64) {
    sc[t] = ssS[t];
    sh[t] = ssS[64 + t];
    bb[t] = sb2[t];
  }
#pragma unroll
  for (int i = 0; i < 16; i++) {
    int ix = t + i * 256;
    Wl[ix >> 6][ix & 63] = sw2[ix];
  }
  __syncthreads();
  int ptb = blockIdx.x * 64;
#pragma unroll
  for (int i = 0; i < 16; i++) {
    int ix = t + i * 256;
    int row = ix >> 6, col = ix & 63;
    float v = ysim[(size_t)ptb * 64 + ix];
    Hl[row][col] = fmaxf(sc[col] * v + sh[col], 0.f);
  }
  __syncthreads();
  int ty = t >> 4, tx = t & 15, r0 = ty * 4, c0 = tx * 4;
  float acc[4][4] = {};
#pragma unroll 4
  for (int j = 0; j < 64; ++j) {
    float a[4], w[4];
#pragma unroll
    for (int i = 0; i < 4; i++) a[i] = Hl[r0 + i][j];
#pragma unroll
    for (int m = 0; m < 4; m++) w[m] = Wl[c0 + m][j];
#pragma unroll
    for (int i = 0; i < 4; i++)
#pragma unroll
      for (int m = 0; m < 4; m++) acc[i][m] += a[i] * w[m];
  }
#pragma unroll
  for (int i = 0; i < 4; i++) {
    float4 v = make_float4(acc[i][0] + bb[c0], acc[i][1] + bb[c0 + 1],
                           acc[i][2] + bb[c0 + 2], acc[i][3] + bb[c0 + 3]);
    *reinterpret_cast<float4*>(sf + (size_t)(ptb + r0 + i) * 64 + c0) = v;
  }
}

// ---------------- YF = [DF|SF] @ fw1^T + fin BN stats ----------------
__global__ __launch_bounds__(256) void yfin_gemm(
    const float* __restrict__ df, const float* __restrict__ sf,
    const float* __restrict__ fw1, float* __restrict__ yf,
    float* __restrict__ accF) {
  __shared__ float Wl[64][129];
  __shared__ float Cl[64][65];
  __shared__ float redS[64], redQ[64];
  int t = threadIdx.x;
  int y = blockIdx.y;
  if (t < 64) {
    redS[t] = 0.f;
    redQ[t] = 0.f;
  }
#pragma unroll
  for (int i = 0; i < 32; i++) {
    int ix = t + i * 256;
    Wl[ix >> 7][ix & 127] = fw1[(size_t)(y * 64 + (ix >> 7)) * 128 + (ix & 127)];
  }
  int ptb = blockIdx.x * 64;
#pragma unroll
  for (int i = 0; i < 16; i++) {
    int ix = t + i * 256;
    Cl[ix >> 6][ix & 63] = df[(size_t)ptb * 64 + ix];
  }
  __syncthreads();
  int ty = t >> 4, tx = t & 15, r0 = ty * 4, c0 = tx * 4;
  float acc[4][4] = {};
#pragma unroll 4
  for (int j = 0; j < 64; ++j) {
    float a[4], w[4];
#pragma unroll
    for (int i = 0; i < 4; i++) a[i] = Cl[r0 + i][j];
#pragma unroll
    for (int m = 0; m < 4; m++) w[m] = Wl[c0 + m][j];
#pragma unroll
    for (int i = 0; i < 4; i++)
#pragma unroll
      for (int m = 0; m < 4; m++) acc[i][m] += a[i] * w[m];
  }
  __syncthreads();
#pragma unroll
  for (int i = 0; i < 16; i++) {
    int ix = t + i * 256;
    Cl[ix >> 6][ix & 63] = sf[(size_t)ptb * 64 + ix];
  }
  __syncthreads();
#pragma unroll 4
  for (int j = 0; j < 64; ++j) {
    float a[4], w[4];
#pragma unroll
    for (int i = 0; i < 4; i++) a[i] = Cl[r0 + i][j];
#pragma unroll
    for (int m = 0; m < 4; m++) w[m] = Wl[c0 + m][64 + j];
#pragma unroll
    for (int i = 0; i < 4; i++)
#pragma unroll
      for (int m = 0; m < 4; m++) acc[i][m] += a[i] * w[m];
  }
#pragma unroll
  for (int i = 0; i < 4; i++) {
    float4 v = make_float4(acc[i][0], acc[i][1], acc[i][2], acc[i][3]);
    *reinterpret_cast<float4*>(yf + (size_t)(ptb + r0 + i) * 128 + y * 64 + c0) = v;
  }
#pragma unroll
  for (int m = 0; m < 4; m++) {
    float s = acc[0][m] + acc[1][m] + acc[2][m] + acc[3][m];
    float qq = acc[0][m] * acc[0][m] + acc[1][m] * acc[1][m] +
               acc[2][m] * acc[2][m] + acc[3][m] * acc[3][m];
    atomicAdd(&redS[c0 + m], s);
    atomicAdd(&redQ[c0 + m], qq);
  }
  __syncthreads();
  if (t < 64) {
    atomicAdd(accF + y * 64 + t, redS[t]);
    atomicAdd(accF + 128 + y * 64 + t, redQ[t]);
  }
}

// ---------------- finalize fin0, fin1 ----------------
__global__ void finalize2(const float* __restrict__ accF, const float* __restrict__ fg,
                          const float* __restrict__ fbeta, float* __restrict__ ssF) {
  int t = threadIdx.x;
  int seg = t >> 7, c = t & 127;
  const float* a = accF + seg * 256;
  float mu = a[c] / (float)NPTS;
  float var = a[128 + c] / (float)NPTS - mu * mu;
  float scale = fg[c] * rsqrtf(var + EPSf);
  ssF[seg * 256 + c] = scale;
  ssF[seg * 256 + 128 + c] = fbeta[c] - mu * scale;
}

// ---------------- out = relu(bn(YF)) @ fw2^T + fb2 ----------------
__global__ __launch_bounds__(256) void finout_gemm(
    const float* __restrict__ yf, const float* __restrict__ ssF,
    const float* __restrict__ fw2, const float* __restrict__ fb2,
    float* __restrict__ outp) {
  __shared__ float Wl[64][129];
  __shared__ float Hl[64][65];
  __shared__ float scl[128], shf[128], bb[64];
  int t = threadIdx.x;
  if (t < 128) {
    scl[t] = ssF[t];
    shf[t] = ssF[128 + t];
  }
  if (t < 64) bb[t] = fb2[t];
#pragma unroll
  for (int i = 0; i < 32; i++) {
    int ix = t + i * 256;
    Wl[ix >> 7][ix & 127] = fw2[ix];
  }
  __syncthreads();
  int ptb = blockIdx.x * 64;
  int ty = t >> 4, tx = t & 15, r0 = ty * 4, c0 = tx * 4;
  float acc[4][4] = {};
#pragma unroll
  for (int i = 0; i < 16; i++) {
    int ix = t + i * 256;
    int row = ix >> 6, jj = ix & 63;
    float v = yf[(size_t)(ptb + row) * 128 + jj];
    Hl[row][jj] = fmaxf(scl[jj] * v + shf[jj], 0.f);
  }
  __syncthreads();
#pragma unroll 4
  for (int j = 0; j < 64; ++j) {
    float a[4], w[4];
#pragma unroll
    for (int i = 0; i < 4; i++) a[i] = Hl[r0 + i][j];
#pragma unroll
    for (int m = 0; m < 4; m++) w[m] = Wl[c0 + m][j];
#pragma unroll
    for (int i = 0; i < 4; i++)
#pragma unroll
      for (int m = 0; m < 4; m++) acc[i][m] += a[i] * w[m];
  }
  __syncthreads();
#pragma unroll
  for (int i = 0; i < 16; i++) {
    int ix = t + i * 256;
    int row = ix >> 6, jj = ix & 63;
    float v = yf[(size_t)(ptb + row) * 128 + 64 + jj];
    Hl[row][jj] = fmaxf(scl[64 + jj] * v + shf[64 + jj], 0.f);
  }
  __syncthreads();
#pragma unroll 4
  for (int j = 0; j < 64; ++j) {
    float a[4], w[4];
#pragma unroll
    for (int i = 0; i < 4; i++) a[i] = Hl[r0 + i][j];
#pragma unroll
    for (int m = 0; m < 4; m++) w[m] = Wl[c0 + m][64 + j];
#pragma unroll
    for (int i = 0; i < 4; i++)
#pragma unroll
      for (int m = 0; m < 4; m++) acc[i][m] += a[i] * w[m];
  }
#pragma unroll
  for (int i = 0; i < 4; i++) {
    float4 v = make_float4(acc[i][0] + bb[c0], acc[i][1] + bb[c0 + 1],
                           acc[i][2] + bb[c0 + 2], acc[i][3] + bb[c0 + 3]);
    *reinterpret_cast<float4*>(outp + (size_t)(ptb + r0 + i) * 64 + c0) = v;
  }
}

extern "C" void kernel_launch(void* const* d_in, const int* in_sizes, int n_in,
                              void* d_out, int out_size, void* d_ws, size_t ws_size,
                              hipStream_t stream) {
  const float* f0 = (const float*)d_in[0];
  const float* f1 = (const float*)d_in[1];
  const int* i01 = (const int*)d_in[2];
  const int* i10 = (const int*)d_in[3];
  const float* dw1 = (const float*)d_in[4];
  const float* dg = (const float*)d_in[6];
  const float* dbe = (const float*)d_in[7];
  const float* dw2 = (const float*)d_in[8];
  const float* db2 = (const float*)d_in[9];
  const float* sw1 = (const float*)d_in[10];
  const float* sg = (const float*)d_in[12];
  const float* sbe = (const float*)d_in[13];
  const float* sw2 = (const float*)d_in[14];
  const float* sb2 = (const float*)d_in[15];
  const float* fw1 = (const float*)d_in[16];
  const float* fg = (const float*)d_in[18];
  const float* fbe = (const float*)d_in[19];
  const float* fw2 = (const float*)d_in[20];
  const float* fb2 = (const float*)d_in[21];

  char* wsb = (char*)d_ws;
  float* out = (float*)d_out;

  char* FT0 = wsb;                          // 16MB
  char* FT1 = wsb + (16u << 20);            // 16MB
  float* acc = (float*)(wsb + (32u << 20)); // 1024 floats
  float* ss = acc + 2048;                   // 1024 floats
  float* YS0 = (float*)(wsb + (32u << 20) + (1u << 16));
  float* YS1 = YS0 + GSZ;
  float* DF0 = YS1 + GSZ;
  float* DF1 = DF0 + GSZ;
  float* SF0 = DF1 + GSZ;
  float* SF1 = SF0 + GSZ;
  float* YF0 = YS0;        // 16MB span over YS0+YS1 (dead after simfeat_gemm)
  float* YF1 = (float*)FT0;  // 16MB over FT0 (dead after diff_out_k)

  hipMemsetAsync(acc, 0, 1024 * sizeof(float), stream);
  gemmG<<<dim3(512, 1, 2), 256, 0, stream>>>(f0, f1, dw1, sw1, FT0, FT1);

  stats_sim<<<1024, 256, 0, stream>>>(FT0, FT1, i01, YS0, acc + 0, acc + 256);
  stats_sim<<<1024, 256, 0, stream>>>(FT1, FT0, i10, YS1, acc + 128, acc + 384);

  finalize1<<<1, 256, 0, stream>>>(acc, dg, dbe, sg, sbe, ss);

  diff_out_k<<<4096, 256, 0, stream>>>(FT0, FT1, i01, dw2, db2, ss + 0, DF0);
  diff_out_k<<<4096, 256, 0, stream>>>(FT1, FT0, i10, dw2, db2, ss + 128, DF1);

  simfeat_gemm<<<512, 256, 0, stream>>>(YS0, ss + 256, sw2, sb2, SF0);
  simfeat_gemm<<<512, 256, 0, stream>>>(YS1, ss + 384, sw2, sb2, SF1);

  yfin_gemm<<<dim3(512, 2), 256, 0, stream>>>(DF0, SF0, fw1, YF0, acc + 512);
  yfin_gemm<<<dim3(512, 2), 256, 0, stream>>>(DF1, SF1, fw1, YF1, acc + 768);

  finalize2<<<1, 256, 0, stream>>>(acc + 512, fg, fbe, ss + 512);

  finout_gemm<<<512, 256, 0, stream>>>(YF0, ss + 512, fw2, fb2, out);
  finout_gemm<<<512, 256, 0, stream>>>(YF1, ss + 768, fw2, fb2, out + (size_t)NPTS * 64);
}